// Round 10
// baseline (423.082 us; speedup 1.0000x reference)
//
#include <hip/hip_runtime.h>

#define N_NODES 100000
#define N_EDGES 800000
#define G_GRAPHS 64
#define F_INPUT 64
#define H_DIM 128
#define C_OUT 4
#define SCAN_BLOCKS ((N_NODES + 255) / 256)   // 391
#define FILL_SEG 8
#define FILL_CHUNKS 125
#define FILL_RANGE (N_NODES / FILL_SEG)        // 12500
#define FILL_CHUNK (N_EDGES / FILL_CHUNKS)     // 6400

typedef __attribute__((ext_vector_type(8))) short bf16x8;
typedef __attribute__((ext_vector_type(8))) unsigned short u16x8;
typedef __attribute__((ext_vector_type(4))) float f32x4;

__device__ inline unsigned short f2bf(float f) {
    union { float f; unsigned int u; } v; v.f = f;
    unsigned int u = v.u + 0x7FFFu + ((v.u >> 16) & 1u);
    return (unsigned short)(u >> 16);
}
__device__ inline float bf2f(unsigned short b) {
    union { unsigned int u; float f; } v; v.u = ((unsigned int)b) << 16;
    return v.f;
}
__device__ inline float2 unpack_pair(unsigned int u) {
    union { unsigned int u; float f; } a, b;
    a.u = u << 16; b.u = u & 0xFFFF0000u;
    float2 r; r.x = a.f; r.y = b.f; return r;
}
__device__ inline unsigned char f2fp8(float v) {
    int r = __builtin_amdgcn_cvt_pk_fp8_f32(v, 0.0f, 0, false);
    return (unsigned char)(r & 0xFF);
}

// ---------------------------------------------------------------------------
// CSR build: histogram + slot assignment
__global__ void hist_kernel(const int* __restrict__ dst, int* __restrict__ cnt,
                            int* __restrict__ slot) {
    int e = blockIdx.x * 256 + threadIdx.x;
    if (e < N_EDGES) slot[e] = atomicAdd(&cnt[dst[e]], 1);
}
__global__ __launch_bounds__(256) void scan1_kernel(
    const int* __restrict__ cnt, int* __restrict__ pre, int* __restrict__ bsum)
{
    __shared__ int tmp[256];
    int i = blockIdx.x * 256 + threadIdx.x;
    int v = (i < N_NODES) ? cnt[i] : 0;
    tmp[threadIdx.x] = v;
    __syncthreads();
    for (int off = 1; off < 256; off <<= 1) {
        int t = (threadIdx.x >= off) ? tmp[threadIdx.x - off] : 0;
        __syncthreads();
        tmp[threadIdx.x] += t;
        __syncthreads();
    }
    if (i < N_NODES) pre[i] = tmp[threadIdx.x] - v;
    if (threadIdx.x == 255) bsum[blockIdx.x] = tmp[255];
}
// scan3x: offs = pre + sum(bsum[0..blockIdx)); dinv; x -> bf16(x*dinv)
__global__ __launch_bounds__(256) void scan3x_kernel(
    const int* __restrict__ pre, const int* __restrict__ bsum,
    const int* __restrict__ cnt, const float4* __restrict__ x4,
    int* __restrict__ offs, float* __restrict__ dinv, unsigned int* __restrict__ xb_u)
{
    __shared__ int red[256];
    __shared__ float dl[256];
    int partial = 0;
    for (int j = threadIdx.x; j < blockIdx.x; j += 256) partial += bsum[j];
    red[threadIdx.x] = partial;
    __syncthreads();
    for (int off = 128; off > 0; off >>= 1) {
        if (threadIdx.x < off) red[threadIdx.x] += red[threadIdx.x + off];
        __syncthreads();
    }
    const int base = red[0];

    int i = blockIdx.x * 256 + threadIdx.x;
    float dv = 0.0f;
    if (i < N_NODES) {
        offs[i] = pre[i] + base;
        dv = rsqrtf((float)cnt[i] + 1.0f);
        dinv[i] = dv;
    }
    if (i == 0) offs[N_NODES] = N_EDGES;
    dl[threadIdx.x] = dv;
    __syncthreads();
    const int row_base = blockIdx.x * 256;
    for (int c = threadIdx.x; c < 256 * 16; c += 256) {
        int r = c >> 4;
        int row = row_base + r;
        if (row < N_NODES) {
            float d2 = dl[r];
            float4 v = x4[(size_t)row * 16 + (c & 15)];
            size_t o = ((size_t)row * 16 + (c & 15)) * 2;
            xb_u[o + 0] = (unsigned int)f2bf(v.x * d2) | ((unsigned int)f2bf(v.y * d2) << 16);
            xb_u[o + 1] = (unsigned int)f2bf(v.z * d2) | ((unsigned int)f2bf(v.w * d2) << 16);
        }
    }
}
// XCD-partitioned atomic-free CSR fill
__global__ __launch_bounds__(256) void fill_kernel(
    const int* __restrict__ src, const int* __restrict__ dst,
    const int* __restrict__ offs, const int* __restrict__ slot,
    int* __restrict__ csr)
{
    const int r  = blockIdx.x & (FILL_SEG - 1);
    const int m  = blockIdx.x >> 3;
    const int lo = r * FILL_RANGE;
    const int hi = lo + FILL_RANGE;
    const int e0 = m * FILL_CHUNK;
    for (int e = e0 + threadIdx.x; e < e0 + FILL_CHUNK; e += 256) {
        int d = dst[e];
        if (d >= lo && d < hi)
            csr[offs[d] + slot[e]] = src[e];
    }
}

// ---------------------------------------------------------------------------
// weights -> split bf16 pairs in MFMA B-fragment order
__device__ inline void wpack_one(const float* __restrict__ W, unsigned short* __restrict__ hi,
                                 unsigned short* __restrict__ lo, int K, int t)
{
    int lane = t & 63;
    int tile = t >> 6;
    int KS = K / 32;
    int ct = tile / KS, ks = tile % KS;
    int n  = ct * 16 + (lane & 15);
    int k0 = ks * 32 + (lane >> 4) * 8;
    #pragma unroll
    for (int j = 0; j < 8; j++) {
        float w = W[(k0 + j) * H_DIM + n];
        unsigned short h = f2bf(w);
        hi[t * 8 + j] = h;
        lo[t * 8 + j] = f2bf(w - bf2f(h));
    }
}
__global__ __launch_bounds__(256) void wpack_all_kernel(
    const float* __restrict__ W1, const float* __restrict__ W2, const float* __restrict__ W3,
    unsigned short* __restrict__ w1hi, unsigned short* __restrict__ w1lo,
    unsigned short* __restrict__ w2hi, unsigned short* __restrict__ w2lo,
    unsigned short* __restrict__ w3hi, unsigned short* __restrict__ w3lo)
{
    int t = blockIdx.x * 256 + threadIdx.x;
    if (t < 1024)       wpack_one(W1, w1hi, w1lo, F_INPUT, t);
    else if (t < 3072)  wpack_one(W2, w2hi, w2lo, H_DIM, t - 1024);
    else if (t < 5120)  wpack_one(W3, w3hi, w3lo, H_DIM, t - 3072);
}

// ---------------------------------------------------------------------------
// MFMA GEMM. A input bf16 or fp8 (converted to bf16 in LDS staging);
// epilogue BIAS_RELU (relu(v+bias)) or v*dinv; output bf16 or fp8.
template <int K, bool BIAS_RELU, bool IN_FP8, bool OUT_FP8>
__global__ __launch_bounds__(256) void mfma_gemm_kernel(
    const void* __restrict__ inv, const unsigned short* __restrict__ whi,
    const unsigned short* __restrict__ wlo, const float* __restrict__ dinv,
    const float* __restrict__ bias, void* __restrict__ outv)
{
    constexpr int KS = K / 32;
    __shared__ unsigned short As[128 * K];

    const int tid  = threadIdx.x;
    const int row0 = blockIdx.x * 128;

    const int CH = 128 * K / 8;
    for (int c = tid; c < CH; c += 256) {
        int mt   = c / (KS * 64);
        int rest = c % (KS * 64);
        int ks   = rest / 64;
        int ln   = rest % 64;
        int r    = mt * 16 + (ln & 15);
        int k    = ks * 32 + (ln >> 4) * 8;
        int gr   = row0 + r; if (gr >= N_NODES) gr = N_NODES - 1;
        if constexpr (IN_FP8) {
            const unsigned char* in8 = (const unsigned char*)inv;
            uint2 t = *(const uint2*)(in8 + (size_t)gr * K + k);
            auto f0 = __builtin_amdgcn_cvt_pk_f32_fp8(t.x, false);
            auto f1 = __builtin_amdgcn_cvt_pk_f32_fp8(t.x, true);
            auto f2 = __builtin_amdgcn_cvt_pk_f32_fp8(t.y, false);
            auto f3 = __builtin_amdgcn_cvt_pk_f32_fp8(t.y, true);
            u16x8 v;
            v[0] = f2bf(f0[0]); v[1] = f2bf(f0[1]);
            v[2] = f2bf(f1[0]); v[3] = f2bf(f1[1]);
            v[4] = f2bf(f2[0]); v[5] = f2bf(f2[1]);
            v[6] = f2bf(f3[0]); v[7] = f2bf(f3[1]);
            *(u16x8*)(As + c * 8) = v;
        } else {
            const unsigned short* in16 = (const unsigned short*)inv;
            *(u16x8*)(As + c * 8) = *(const u16x8*)(in16 + (size_t)gr * K + k);
        }
    }
    __syncthreads();

    const int w = tid >> 6, lane = tid & 63;
    const int quad = lane >> 4, l16 = lane & 15;

    f32x4 acc[2][8];
    #pragma unroll
    for (int rt = 0; rt < 2; rt++)
        #pragma unroll
        for (int ct = 0; ct < 8; ct++) acc[rt][ct] = (f32x4)(0.0f);

    #pragma unroll
    for (int ks = 0; ks < KS; ks++) {
        bf16x8 a0 = *(const bf16x8*)(As + (((w * 2 + 0) * KS + ks) * 64 + lane) * 8);
        bf16x8 a1 = *(const bf16x8*)(As + (((w * 2 + 1) * KS + ks) * 64 + lane) * 8);
        bf16x8 bh[8], bl[8];
        #pragma unroll
        for (int ct = 0; ct < 8; ct++) {
            bh[ct] = *(const bf16x8*)(whi + ((size_t)(ct * KS + ks) * 64 + lane) * 8);
            bl[ct] = *(const bf16x8*)(wlo + ((size_t)(ct * KS + ks) * 64 + lane) * 8);
        }
        #pragma unroll
        for (int ct = 0; ct < 8; ct++) {
            acc[0][ct] = __builtin_amdgcn_mfma_f32_16x16x32_bf16(a0, bh[ct], acc[0][ct], 0, 0, 0);
            acc[0][ct] = __builtin_amdgcn_mfma_f32_16x16x32_bf16(a0, bl[ct], acc[0][ct], 0, 0, 0);
            acc[1][ct] = __builtin_amdgcn_mfma_f32_16x16x32_bf16(a1, bh[ct], acc[1][ct], 0, 0, 0);
            acc[1][ct] = __builtin_amdgcn_mfma_f32_16x16x32_bf16(a1, bl[ct], acc[1][ct], 0, 0, 0);
        }
    }

    float bv[8];
    if (BIAS_RELU) {
        #pragma unroll
        for (int ct = 0; ct < 8; ct++) bv[ct] = bias[ct * 16 + l16];
    }

    #pragma unroll
    for (int rt = 0; rt < 2; rt++) {
        #pragma unroll
        for (int reg = 0; reg < 4; reg++) {
            int row = row0 + w * 32 + rt * 16 + quad * 4 + reg;
            if (row < N_NODES) {
                float dv = BIAS_RELU ? 0.0f : dinv[row];
                #pragma unroll
                for (int ct = 0; ct < 8; ct++) {
                    float val;
                    if (BIAS_RELU) val = fmaxf(acc[rt][ct][reg] + bv[ct], 0.0f);
                    else           val = acc[rt][ct][reg] * dv;
                    if constexpr (OUT_FP8) {
                        ((unsigned char*)outv)[(size_t)row * H_DIM + ct * 16 + l16] = f2fp8(val);
                    } else {
                        ((unsigned short*)outv)[(size_t)row * H_DIM + ct * 16 + l16] = f2bf(val);
                    }
                }
            }
        }
    }
}

// ---------------------------------------------------------------------------
// bf16 gather (layer 1, 64-dim): thread = (node, feature-pair), unroll 8/4/1
__global__ __launch_bounds__(256) void gather_bf16_kernel(
    const unsigned int* __restrict__ hs_u, const int* __restrict__ offs,
    const int* __restrict__ csr, const float* __restrict__ dinv,
    unsigned int* __restrict__ outb)
{
    const int F2 = 32;
    int idx = blockIdx.x * 256 + threadIdx.x;
    int i  = idx >> 5;
    int f2 = idx & (F2 - 1);
    int beg = offs[i];
    int end = offs[i + 1];
    float2 acc = unpack_pair(hs_u[(size_t)i * F2 + f2]);
    int e = beg;
    while (e + 8 <= end) {
        int s0 = csr[e+0], s1 = csr[e+1], s2 = csr[e+2], s3 = csr[e+3];
        int s4 = csr[e+4], s5 = csr[e+5], s6 = csr[e+6], s7 = csr[e+7];
        float2 v0 = unpack_pair(hs_u[(size_t)s0 * F2 + f2]);
        float2 v1 = unpack_pair(hs_u[(size_t)s1 * F2 + f2]);
        float2 v2 = unpack_pair(hs_u[(size_t)s2 * F2 + f2]);
        float2 v3 = unpack_pair(hs_u[(size_t)s3 * F2 + f2]);
        float2 v4 = unpack_pair(hs_u[(size_t)s4 * F2 + f2]);
        float2 v5 = unpack_pair(hs_u[(size_t)s5 * F2 + f2]);
        float2 v6 = unpack_pair(hs_u[(size_t)s6 * F2 + f2]);
        float2 v7 = unpack_pair(hs_u[(size_t)s7 * F2 + f2]);
        acc.x += ((v0.x + v1.x) + (v2.x + v3.x)) + ((v4.x + v5.x) + (v6.x + v7.x));
        acc.y += ((v0.y + v1.y) + (v2.y + v3.y)) + ((v4.y + v5.y) + (v6.y + v7.y));
        e += 8;
    }
    if (e + 4 <= end) {
        int s0 = csr[e+0], s1 = csr[e+1], s2 = csr[e+2], s3 = csr[e+3];
        float2 v0 = unpack_pair(hs_u[(size_t)s0 * F2 + f2]);
        float2 v1 = unpack_pair(hs_u[(size_t)s1 * F2 + f2]);
        float2 v2 = unpack_pair(hs_u[(size_t)s2 * F2 + f2]);
        float2 v3 = unpack_pair(hs_u[(size_t)s3 * F2 + f2]);
        acc.x += (v0.x + v1.x) + (v2.x + v3.x);
        acc.y += (v0.y + v1.y) + (v2.y + v3.y);
        e += 4;
    }
    while (e < end) {
        int s = csr[e++];
        float2 v = unpack_pair(hs_u[(size_t)s * F2 + f2]);
        acc.x += v.x; acc.y += v.y;
    }
    float dv = dinv[i];
    outb[idx] = (unsigned int)f2bf(acc.x * dv) | ((unsigned int)f2bf(acc.y * dv) << 16);
}

// ---------------------------------------------------------------------------
// fp8 gather core: accumulate self + neighbor rows for (node i, dword f4)
__device__ inline void gather_fp8_acc(
    const unsigned int* __restrict__ base, const int* __restrict__ csr,
    int i, int beg, int end, float& a0, float& a1, float& a2, float& a3)
{
    {
        unsigned int w = base[(size_t)i * 32];
        auto lo = __builtin_amdgcn_cvt_pk_f32_fp8(w, false);
        auto hi = __builtin_amdgcn_cvt_pk_f32_fp8(w, true);
        a0 += lo[0]; a1 += lo[1]; a2 += hi[0]; a3 += hi[1];
    }
    int e = beg;
    while (e + 8 <= end) {
        unsigned int w0 = base[(size_t)csr[e+0] * 32];
        unsigned int w1 = base[(size_t)csr[e+1] * 32];
        unsigned int w2 = base[(size_t)csr[e+2] * 32];
        unsigned int w3 = base[(size_t)csr[e+3] * 32];
        unsigned int w4 = base[(size_t)csr[e+4] * 32];
        unsigned int w5 = base[(size_t)csr[e+5] * 32];
        unsigned int w6 = base[(size_t)csr[e+6] * 32];
        unsigned int w7 = base[(size_t)csr[e+7] * 32];
        #pragma unroll
        for (unsigned int w : {w0, w1, w2, w3, w4, w5, w6, w7}) {
            auto lo = __builtin_amdgcn_cvt_pk_f32_fp8(w, false);
            auto hi = __builtin_amdgcn_cvt_pk_f32_fp8(w, true);
            a0 += lo[0]; a1 += lo[1]; a2 += hi[0]; a3 += hi[1];
        }
        e += 8;
    }
    if (e + 4 <= end) {
        unsigned int w0 = base[(size_t)csr[e+0] * 32];
        unsigned int w1 = base[(size_t)csr[e+1] * 32];
        unsigned int w2 = base[(size_t)csr[e+2] * 32];
        unsigned int w3 = base[(size_t)csr[e+3] * 32];
        #pragma unroll
        for (unsigned int w : {w0, w1, w2, w3}) {
            auto lo = __builtin_amdgcn_cvt_pk_f32_fp8(w, false);
            auto hi = __builtin_amdgcn_cvt_pk_f32_fp8(w, true);
            a0 += lo[0]; a1 += lo[1]; a2 += hi[0]; a3 += hi[1];
        }
        e += 4;
    }
    while (e < end) {
        unsigned int w = base[(size_t)csr[e++] * 32];
        auto lo = __builtin_amdgcn_cvt_pk_f32_fp8(w, false);
        auto hi = __builtin_amdgcn_cvt_pk_f32_fp8(w, true);
        a0 += lo[0]; a1 += lo[1]; a2 += hi[0]; a3 += hi[1];
    }
}

// layer-2 gather: fp8 in -> bias+relu -> fp8 out
__global__ __launch_bounds__(256) void gather_fp8_kernel(
    const unsigned int* __restrict__ hs8, const int* __restrict__ offs,
    const int* __restrict__ csr, const float* __restrict__ dinv,
    const float* __restrict__ bias, unsigned int* __restrict__ out8)
{
    int idx = blockIdx.x * 256 + threadIdx.x;
    int i  = idx >> 5;
    int f4 = idx & 31;
    const unsigned int* base = hs8 + f4;
    float a0 = 0, a1 = 0, a2 = 0, a3 = 0;
    gather_fp8_acc(base, csr, i, offs[i], offs[i + 1], a0, a1, a2, a3);
    float dv = dinv[i];
    float4 bv = *(const float4*)(bias + f4 * 4);
    float v0 = fmaxf(a0 * dv + bv.x, 0.0f);
    float v1 = fmaxf(a1 * dv + bv.y, 0.0f);
    float v2 = fmaxf(a2 * dv + bv.z, 0.0f);
    float v3 = fmaxf(a3 * dv + bv.w, 0.0f);
    int d = __builtin_amdgcn_cvt_pk_fp8_f32(v0, v1, 0, false);
    d = __builtin_amdgcn_cvt_pk_fp8_f32(v2, v3, d, true);
    out8[(size_t)i * 32 + f4] = (unsigned int)d;
}

// layer-3 gather fused with mean-pool: fp8 in -> bias -> atomic pool accumulate
__global__ __launch_bounds__(256) void gather3_pool_kernel(
    const unsigned int* __restrict__ hs8, const int* __restrict__ offs,
    const int* __restrict__ csr, const float* __restrict__ dinv,
    const float* __restrict__ bias, const int* __restrict__ batch,
    float* __restrict__ s, float* __restrict__ cnt)
{
    __shared__ float sl[H_DIM];
    const int tid = threadIdx.x;
    if (tid < H_DIM) sl[tid] = 0.0f;
    __syncthreads();

    int i  = blockIdx.x * 8 + (tid >> 5);
    int f4 = tid & 31;
    const unsigned int* base = hs8 + f4;
    float a0 = 0, a1 = 0, a2 = 0, a3 = 0;
    gather_fp8_acc(base, csr, i, offs[i], offs[i + 1], a0, a1, a2, a3);
    float dv = dinv[i];
    float4 bv = *(const float4*)(bias + f4 * 4);
    float v0 = a0 * dv + bv.x;
    float v1 = a1 * dv + bv.y;
    float v2 = a2 * dv + bv.z;
    float v3 = a3 * dv + bv.w;

    int g0 = batch[blockIdx.x * 8];
    int g7 = batch[blockIdx.x * 8 + 7];
    if (g0 == g7) {
        atomicAdd(&sl[f4 * 4 + 0], v0);
        atomicAdd(&sl[f4 * 4 + 1], v1);
        atomicAdd(&sl[f4 * 4 + 2], v2);
        atomicAdd(&sl[f4 * 4 + 3], v3);
        __syncthreads();
        if (tid < H_DIM) unsafeAtomicAdd(&s[g0 * H_DIM + tid], sl[tid]);
        if (tid == 0) unsafeAtomicAdd(&cnt[g0], 8.0f);
    } else {
        int g = batch[i];
        unsafeAtomicAdd(&s[g * H_DIM + f4 * 4 + 0], v0);
        unsafeAtomicAdd(&s[g * H_DIM + f4 * 4 + 1], v1);
        unsafeAtomicAdd(&s[g * H_DIM + f4 * 4 + 2], v2);
        unsafeAtomicAdd(&s[g * H_DIM + f4 * 4 + 3], v3);
        if (f4 == 0) unsafeAtomicAdd(&cnt[g], 1.0f);
    }
}

// ---------------------------------------------------------------------------
__global__ __launch_bounds__(128) void mlp_kernel(
    const float* __restrict__ s, const float* __restrict__ cnt,
    const float* __restrict__ fw1, const float* __restrict__ fb1,
    const float* __restrict__ fw2, const float* __restrict__ fb2,
    float* __restrict__ out)
{
    __shared__ float p[H_DIM];
    __shared__ float z[H_DIM];
    int g = blockIdx.x;
    int f = threadIdx.x;
    float c = fmaxf(cnt[g], 1.0f);
    p[f] = s[g * H_DIM + f] / c;
    __syncthreads();
    float acc = fb1[f];
    for (int k = 0; k < H_DIM; k++) acc = fmaf(p[k], fw1[k * H_DIM + f], acc);
    z[f] = fmaxf(acc, 0.0f);
    __syncthreads();
    if (f < C_OUT) {
        float o = fb2[f];
        for (int k = 0; k < H_DIM; k++) o = fmaf(z[k], fw2[k * C_OUT + f], o);
        out[g * C_OUT + f] = o;
    }
}

// ---------------------------------------------------------------------------
extern "C" void kernel_launch(void* const* d_in, const int* in_sizes, int n_in,
                              void* d_out, int out_size, void* d_ws, size_t ws_size,
                              hipStream_t stream)
{
    const float* x   = (const float*)d_in[0];
    const float* W1  = (const float*)d_in[1];
    const float* b1  = (const float*)d_in[2];
    const float* W2  = (const float*)d_in[3];
    const float* b2  = (const float*)d_in[4];
    const float* W3  = (const float*)d_in[5];
    const float* b3  = (const float*)d_in[6];
    const float* fw1 = (const float*)d_in[7];
    const float* fb1 = (const float*)d_in[8];
    const float* fw2 = (const float*)d_in[9];
    const float* fb2 = (const float*)d_in[10];
    const int*   ei  = (const int*)d_in[11];
    const int*   bat = (const int*)d_in[12];
    const int* esrc = ei;
    const int* edst = ei + N_EDGES;
    float* out = (float*)d_out;

    // workspace layout
    char* ws = (char*)d_ws;
    unsigned short* xb   = (unsigned short*)ws;  ws += (size_t)N_NODES * F_INPUT * 2; // 12.8MB
    unsigned short* aggA = (unsigned short*)ws;  ws += (size_t)N_NODES * F_INPUT * 2; // 12.8MB
    unsigned char*  p0   = (unsigned char*)ws;   ws += (size_t)N_NODES * H_DIM;       // 12.8MB
    unsigned char*  p1   = (unsigned char*)ws;   ws += (size_t)N_NODES * H_DIM;       // 12.8MB
    unsigned char*  p2   = (unsigned char*)ws;   ws += (size_t)N_NODES * H_DIM;       // 12.8MB
    unsigned short* w1hi = (unsigned short*)ws;  ws += H_DIM * F_INPUT * 2;
    unsigned short* w1lo = (unsigned short*)ws;  ws += H_DIM * F_INPUT * 2;
    unsigned short* w2hi = (unsigned short*)ws;  ws += H_DIM * H_DIM * 2;
    unsigned short* w2lo = (unsigned short*)ws;  ws += H_DIM * H_DIM * 2;
    unsigned short* w3hi = (unsigned short*)ws;  ws += H_DIM * H_DIM * 2;
    unsigned short* w3lo = (unsigned short*)ws;  ws += H_DIM * H_DIM * 2;
    float* dinv = (float*)ws;  ws += N_NODES * 4;
    int* pre    = (int*)ws;    ws += N_NODES * 4;
    int* offs   = (int*)ws;    ws += (N_NODES + 1) * 4;
    int* bsum   = (int*)ws;    ws += (SCAN_BLOCKS + 1) * 4;
    int* slot   = (int*)ws;    ws += (size_t)N_EDGES * 4;
    int* csr    = (int*)ws;    ws += (size_t)N_EDGES * 4;
    // zero-init region (single memset): cnti | s | cnt
    int*   cnti = (int*)ws;    ws += N_NODES * 4;
    float* s    = (float*)ws;  ws += G_GRAPHS * H_DIM * 4;
    float* cnt  = (float*)ws;  ws += G_GRAPHS * 4;

    hipMemsetAsync(cnti, 0, (N_NODES + G_GRAPHS * H_DIM + G_GRAPHS) * sizeof(int), stream);

    // CSR build + dinv + x conversion
    const int egrid = (N_EDGES + 255) / 256;
    hist_kernel<<<egrid, 256, 0, stream>>>(edst, cnti, slot);
    scan1_kernel<<<SCAN_BLOCKS, 256, 0, stream>>>(cnti, pre, bsum);
    scan3x_kernel<<<SCAN_BLOCKS, 256, 0, stream>>>(
        pre, bsum, cnti, (const float4*)x, offs, dinv, (unsigned int*)xb);
    fill_kernel<<<FILL_SEG * FILL_CHUNKS, 256, 0, stream>>>(esrc, edst, offs, slot, csr);

    wpack_all_kernel<<<20, 256, 0, stream>>>(W1, W2, W3, w1hi, w1lo, w2hi, w2lo, w3hi, w3lo);

    const int gemm_grid = (N_NODES + 127) / 128;        // 782
    const int gath_grid = (N_NODES * 32) / 256;         // 12500

    // layer 1: aggregate-first (bf16 64-dim), GEMM bias+relu -> fp8
    gather_bf16_kernel<<<gath_grid, 256, 0, stream>>>(
        (const unsigned int*)xb, offs, csr, dinv, (unsigned int*)aggA);
    mfma_gemm_kernel<64, true, false, true><<<gemm_grid, 256, 0, stream>>>(
        aggA, w1hi, w1lo, dinv, b1, p0);
    // layer 2: GEMM (fp8-A, dinv) -> fp8; gather (bias+relu) -> fp8
    mfma_gemm_kernel<128, false, true, true><<<gemm_grid, 256, 0, stream>>>(
        p0, w2hi, w2lo, dinv, nullptr, p1);
    gather_fp8_kernel<<<gath_grid, 256, 0, stream>>>(
        (const unsigned int*)p1, offs, csr, dinv, b2, (unsigned int*)p2);
    // layer 3: GEMM (fp8-A, dinv) -> fp8; fused gather+pool
    mfma_gemm_kernel<128, false, true, true><<<gemm_grid, 256, 0, stream>>>(
        p2, w3hi, w3lo, dinv, nullptr, p0);
    gather3_pool_kernel<<<N_NODES / 8, 256, 0, stream>>>(
        (const unsigned int*)p0, offs, csr, dinv, b3, bat, s, cnt);

    // MLP head
    mlp_kernel<<<G_GRAPHS, 128, 0, stream>>>(s, cnt, fw1, fb1, fw2, fb2, out);
}

// Round 12
// 344.664 us; speedup vs baseline: 1.2275x; 1.2275x over previous
//
#include <hip/hip_runtime.h>

#define N_NODES 100000
#define N_EDGES 800000
#define G_GRAPHS 64
#define F_INPUT 64
#define H_DIM 128
#define C_OUT 4
#define SCAN_BLOCKS ((N_NODES + 255) / 256)   // 391
#define FILL_SEG 8
#define FILL_CHUNKS 125
#define FILL_RANGE (N_NODES / FILL_SEG)        // 12500
#define FILL_CHUNK (N_EDGES / FILL_CHUNKS)     // 6400

typedef __attribute__((ext_vector_type(8))) short bf16x8;
typedef __attribute__((ext_vector_type(8))) unsigned short u16x8;
typedef __attribute__((ext_vector_type(4))) float f32x4;

__device__ inline unsigned short f2bf(float f) {
    union { float f; unsigned int u; } v; v.f = f;
    unsigned int u = v.u + 0x7FFFu + ((v.u >> 16) & 1u);
    return (unsigned short)(u >> 16);
}
__device__ inline float bf2f(unsigned short b) {
    union { unsigned int u; float f; } v; v.u = ((unsigned int)b) << 16;
    return v.f;
}
__device__ inline float2 unpack_pair(unsigned int u) {
    union { unsigned int u; float f; } a, b;
    a.u = u << 16; b.u = u & 0xFFFF0000u;
    float2 r; r.x = a.f; r.y = b.f; return r;
}
__device__ inline unsigned char f2fp8(float v) {
    int r = __builtin_amdgcn_cvt_pk_fp8_f32(v, 0.0f, 0, false);
    return (unsigned char)(r & 0xFF);
}

// ---------------------------------------------------------------------------
// CSR build: histogram + slot assignment
__global__ void hist_kernel(const int* __restrict__ dst, int* __restrict__ cnt,
                            int* __restrict__ slot) {
    int e = blockIdx.x * 256 + threadIdx.x;
    if (e < N_EDGES) slot[e] = atomicAdd(&cnt[dst[e]], 1);
}
__global__ __launch_bounds__(256) void scan1_kernel(
    const int* __restrict__ cnt, int* __restrict__ pre, int* __restrict__ bsum)
{
    __shared__ int tmp[256];
    int i = blockIdx.x * 256 + threadIdx.x;
    int v = (i < N_NODES) ? cnt[i] : 0;
    tmp[threadIdx.x] = v;
    __syncthreads();
    for (int off = 1; off < 256; off <<= 1) {
        int t = (threadIdx.x >= off) ? tmp[threadIdx.x - off] : 0;
        __syncthreads();
        tmp[threadIdx.x] += t;
        __syncthreads();
    }
    if (i < N_NODES) pre[i] = tmp[threadIdx.x] - v;
    if (threadIdx.x == 255) bsum[blockIdx.x] = tmp[255];
}
// scan3x: offs = pre + sum(bsum[0..blockIdx)); dinv; x -> bf16(x*dinv)
__global__ __launch_bounds__(256) void scan3x_kernel(
    const int* __restrict__ pre, const int* __restrict__ bsum,
    const int* __restrict__ cnt, const float4* __restrict__ x4,
    int* __restrict__ offs, float* __restrict__ dinv, unsigned int* __restrict__ xb_u)
{
    __shared__ int red[256];
    __shared__ float dl[256];
    int partial = 0;
    for (int j = threadIdx.x; j < blockIdx.x; j += 256) partial += bsum[j];
    red[threadIdx.x] = partial;
    __syncthreads();
    for (int off = 128; off > 0; off >>= 1) {
        if (threadIdx.x < off) red[threadIdx.x] += red[threadIdx.x + off];
        __syncthreads();
    }
    const int base = red[0];

    int i = blockIdx.x * 256 + threadIdx.x;
    float dv = 0.0f;
    if (i < N_NODES) {
        offs[i] = pre[i] + base;
        dv = rsqrtf((float)cnt[i] + 1.0f);
        dinv[i] = dv;
    }
    if (i == 0) offs[N_NODES] = N_EDGES;
    dl[threadIdx.x] = dv;
    __syncthreads();
    const int row_base = blockIdx.x * 256;
    for (int c = threadIdx.x; c < 256 * 16; c += 256) {
        int r = c >> 4;
        int row = row_base + r;
        if (row < N_NODES) {
            float d2 = dl[r];
            float4 v = x4[(size_t)row * 16 + (c & 15)];
            size_t o = ((size_t)row * 16 + (c & 15)) * 2;
            xb_u[o + 0] = (unsigned int)f2bf(v.x * d2) | ((unsigned int)f2bf(v.y * d2) << 16);
            xb_u[o + 1] = (unsigned int)f2bf(v.z * d2) | ((unsigned int)f2bf(v.w * d2) << 16);
        }
    }
}
// XCD-partitioned atomic-free CSR fill
__global__ __launch_bounds__(256) void fill_kernel(
    const int* __restrict__ src, const int* __restrict__ dst,
    const int* __restrict__ offs, const int* __restrict__ slot,
    int* __restrict__ csr)
{
    const int r  = blockIdx.x & (FILL_SEG - 1);
    const int m  = blockIdx.x >> 3;
    const int lo = r * FILL_RANGE;
    const int hi = lo + FILL_RANGE;
    const int e0 = m * FILL_CHUNK;
    for (int e = e0 + threadIdx.x; e < e0 + FILL_CHUNK; e += 256) {
        int d = dst[e];
        if (d >= lo && d < hi)
            csr[offs[d] + slot[e]] = src[e];
    }
}

// ---------------------------------------------------------------------------
// weights -> split bf16 pairs in MFMA B-fragment order
__device__ inline void wpack_one(const float* __restrict__ W, unsigned short* __restrict__ hi,
                                 unsigned short* __restrict__ lo, int K, int t)
{
    int lane = t & 63;
    int tile = t >> 6;
    int KS = K / 32;
    int ct = tile / KS, ks = tile % KS;
    int n  = ct * 16 + (lane & 15);
    int k0 = ks * 32 + (lane >> 4) * 8;
    #pragma unroll
    for (int j = 0; j < 8; j++) {
        float w = W[(k0 + j) * H_DIM + n];
        unsigned short h = f2bf(w);
        hi[t * 8 + j] = h;
        lo[t * 8 + j] = f2bf(w - bf2f(h));
    }
}
__global__ __launch_bounds__(256) void wpack_all_kernel(
    const float* __restrict__ W1, const float* __restrict__ W2, const float* __restrict__ W3,
    unsigned short* __restrict__ w1hi, unsigned short* __restrict__ w1lo,
    unsigned short* __restrict__ w2hi, unsigned short* __restrict__ w2lo,
    unsigned short* __restrict__ w3hi, unsigned short* __restrict__ w3lo)
{
    int t = blockIdx.x * 256 + threadIdx.x;
    if (t < 1024)       wpack_one(W1, w1hi, w1lo, F_INPUT, t);
    else if (t < 3072)  wpack_one(W2, w2hi, w2lo, H_DIM, t - 1024);
    else if (t < 5120)  wpack_one(W3, w3hi, w3lo, H_DIM, t - 3072);
}

// ---------------------------------------------------------------------------
// MFMA GEMM. A input bf16 or fp8 (converted to bf16 in LDS staging);
// epilogue BIAS_RELU (relu(v+bias)) or v*dinv; output bf16 or fp8.
template <int K, bool BIAS_RELU, bool IN_FP8, bool OUT_FP8>
__global__ __launch_bounds__(256) void mfma_gemm_kernel(
    const void* __restrict__ inv, const unsigned short* __restrict__ whi,
    const unsigned short* __restrict__ wlo, const float* __restrict__ dinv,
    const float* __restrict__ bias, void* __restrict__ outv)
{
    constexpr int KS = K / 32;
    __shared__ unsigned short As[128 * K];

    const int tid  = threadIdx.x;
    const int row0 = blockIdx.x * 128;

    const int CH = 128 * K / 8;
    for (int c = tid; c < CH; c += 256) {
        int mt   = c / (KS * 64);
        int rest = c % (KS * 64);
        int ks   = rest / 64;
        int ln   = rest % 64;
        int r    = mt * 16 + (ln & 15);
        int k    = ks * 32 + (ln >> 4) * 8;
        int gr   = row0 + r; if (gr >= N_NODES) gr = N_NODES - 1;
        if constexpr (IN_FP8) {
            const unsigned char* in8 = (const unsigned char*)inv;
            uint2 t = *(const uint2*)(in8 + (size_t)gr * K + k);
            auto f0 = __builtin_amdgcn_cvt_pk_f32_fp8(t.x, false);
            auto f1 = __builtin_amdgcn_cvt_pk_f32_fp8(t.x, true);
            auto f2 = __builtin_amdgcn_cvt_pk_f32_fp8(t.y, false);
            auto f3 = __builtin_amdgcn_cvt_pk_f32_fp8(t.y, true);
            u16x8 v;
            v[0] = f2bf(f0[0]); v[1] = f2bf(f0[1]);
            v[2] = f2bf(f1[0]); v[3] = f2bf(f1[1]);
            v[4] = f2bf(f2[0]); v[5] = f2bf(f2[1]);
            v[6] = f2bf(f3[0]); v[7] = f2bf(f3[1]);
            *(u16x8*)(As + c * 8) = v;
        } else {
            const unsigned short* in16 = (const unsigned short*)inv;
            *(u16x8*)(As + c * 8) = *(const u16x8*)(in16 + (size_t)gr * K + k);
        }
    }
    __syncthreads();

    const int w = tid >> 6, lane = tid & 63;
    const int quad = lane >> 4, l16 = lane & 15;

    f32x4 acc[2][8];
    #pragma unroll
    for (int rt = 0; rt < 2; rt++)
        #pragma unroll
        for (int ct = 0; ct < 8; ct++) acc[rt][ct] = (f32x4)(0.0f);

    #pragma unroll
    for (int ks = 0; ks < KS; ks++) {
        bf16x8 a0 = *(const bf16x8*)(As + (((w * 2 + 0) * KS + ks) * 64 + lane) * 8);
        bf16x8 a1 = *(const bf16x8*)(As + (((w * 2 + 1) * KS + ks) * 64 + lane) * 8);
        bf16x8 bh[8], bl[8];
        #pragma unroll
        for (int ct = 0; ct < 8; ct++) {
            bh[ct] = *(const bf16x8*)(whi + ((size_t)(ct * KS + ks) * 64 + lane) * 8);
            bl[ct] = *(const bf16x8*)(wlo + ((size_t)(ct * KS + ks) * 64 + lane) * 8);
        }
        #pragma unroll
        for (int ct = 0; ct < 8; ct++) {
            acc[0][ct] = __builtin_amdgcn_mfma_f32_16x16x32_bf16(a0, bh[ct], acc[0][ct], 0, 0, 0);
            acc[0][ct] = __builtin_amdgcn_mfma_f32_16x16x32_bf16(a0, bl[ct], acc[0][ct], 0, 0, 0);
            acc[1][ct] = __builtin_amdgcn_mfma_f32_16x16x32_bf16(a1, bh[ct], acc[1][ct], 0, 0, 0);
            acc[1][ct] = __builtin_amdgcn_mfma_f32_16x16x32_bf16(a1, bl[ct], acc[1][ct], 0, 0, 0);
        }
    }

    float bv[8];
    if (BIAS_RELU) {
        #pragma unroll
        for (int ct = 0; ct < 8; ct++) bv[ct] = bias[ct * 16 + l16];
    }

    #pragma unroll
    for (int rt = 0; rt < 2; rt++) {
        #pragma unroll
        for (int reg = 0; reg < 4; reg++) {
            int row = row0 + w * 32 + rt * 16 + quad * 4 + reg;
            if (row < N_NODES) {
                float dv = BIAS_RELU ? 0.0f : dinv[row];
                #pragma unroll
                for (int ct = 0; ct < 8; ct++) {
                    float val;
                    if (BIAS_RELU) val = fmaxf(acc[rt][ct][reg] + bv[ct], 0.0f);
                    else           val = acc[rt][ct][reg] * dv;
                    if constexpr (OUT_FP8) {
                        ((unsigned char*)outv)[(size_t)row * H_DIM + ct * 16 + l16] = f2fp8(val);
                    } else {
                        ((unsigned short*)outv)[(size_t)row * H_DIM + ct * 16 + l16] = f2bf(val);
                    }
                }
            }
        }
    }
}

// ---------------------------------------------------------------------------
// bf16 gather (layer 1, 64-dim): thread = (node, feature-pair), unroll 8/4/1
__global__ __launch_bounds__(256) void gather_bf16_kernel(
    const unsigned int* __restrict__ hs_u, const int* __restrict__ offs,
    const int* __restrict__ csr, const float* __restrict__ dinv,
    unsigned int* __restrict__ outb)
{
    const int F2 = 32;
    int idx = blockIdx.x * 256 + threadIdx.x;
    int i  = idx >> 5;
    int f2 = idx & (F2 - 1);
    int beg = offs[i];
    int end = offs[i + 1];
    float2 acc = unpack_pair(hs_u[(size_t)i * F2 + f2]);
    int e = beg;
    while (e + 8 <= end) {
        int s0 = csr[e+0], s1 = csr[e+1], s2 = csr[e+2], s3 = csr[e+3];
        int s4 = csr[e+4], s5 = csr[e+5], s6 = csr[e+6], s7 = csr[e+7];
        float2 v0 = unpack_pair(hs_u[(size_t)s0 * F2 + f2]);
        float2 v1 = unpack_pair(hs_u[(size_t)s1 * F2 + f2]);
        float2 v2 = unpack_pair(hs_u[(size_t)s2 * F2 + f2]);
        float2 v3 = unpack_pair(hs_u[(size_t)s3 * F2 + f2]);
        float2 v4 = unpack_pair(hs_u[(size_t)s4 * F2 + f2]);
        float2 v5 = unpack_pair(hs_u[(size_t)s5 * F2 + f2]);
        float2 v6 = unpack_pair(hs_u[(size_t)s6 * F2 + f2]);
        float2 v7 = unpack_pair(hs_u[(size_t)s7 * F2 + f2]);
        acc.x += ((v0.x + v1.x) + (v2.x + v3.x)) + ((v4.x + v5.x) + (v6.x + v7.x));
        acc.y += ((v0.y + v1.y) + (v2.y + v3.y)) + ((v4.y + v5.y) + (v6.y + v7.y));
        e += 8;
    }
    if (e + 4 <= end) {
        int s0 = csr[e+0], s1 = csr[e+1], s2 = csr[e+2], s3 = csr[e+3];
        float2 v0 = unpack_pair(hs_u[(size_t)s0 * F2 + f2]);
        float2 v1 = unpack_pair(hs_u[(size_t)s1 * F2 + f2]);
        float2 v2 = unpack_pair(hs_u[(size_t)s2 * F2 + f2]);
        float2 v3 = unpack_pair(hs_u[(size_t)s3 * F2 + f2]);
        acc.x += (v0.x + v1.x) + (v2.x + v3.x);
        acc.y += (v0.y + v1.y) + (v2.y + v3.y);
        e += 4;
    }
    while (e < end) {
        int s = csr[e++];
        float2 v = unpack_pair(hs_u[(size_t)s * F2 + f2]);
        acc.x += v.x; acc.y += v.y;
    }
    float dv = dinv[i];
    outb[idx] = (unsigned int)f2bf(acc.x * dv) | ((unsigned int)f2bf(acc.y * dv) << 16);
}

// ---------------------------------------------------------------------------
// fp8 gather core: accumulate self + neighbor rows for (node i, dword f4)
__device__ inline void gather_fp8_acc(
    const unsigned int* __restrict__ base, const int* __restrict__ csr,
    int i, int beg, int end, float& a0, float& a1, float& a2, float& a3)
{
    {
        unsigned int w = base[(size_t)i * 32];
        auto lo = __builtin_amdgcn_cvt_pk_f32_fp8(w, false);
        auto hi = __builtin_amdgcn_cvt_pk_f32_fp8(w, true);
        a0 += lo[0]; a1 += lo[1]; a2 += hi[0]; a3 += hi[1];
    }
    int e = beg;
    while (e + 8 <= end) {
        unsigned int w0 = base[(size_t)csr[e+0] * 32];
        unsigned int w1 = base[(size_t)csr[e+1] * 32];
        unsigned int w2 = base[(size_t)csr[e+2] * 32];
        unsigned int w3 = base[(size_t)csr[e+3] * 32];
        unsigned int w4 = base[(size_t)csr[e+4] * 32];
        unsigned int w5 = base[(size_t)csr[e+5] * 32];
        unsigned int w6 = base[(size_t)csr[e+6] * 32];
        unsigned int w7 = base[(size_t)csr[e+7] * 32];
        #pragma unroll
        for (unsigned int w : {w0, w1, w2, w3, w4, w5, w6, w7}) {
            auto lo = __builtin_amdgcn_cvt_pk_f32_fp8(w, false);
            auto hi = __builtin_amdgcn_cvt_pk_f32_fp8(w, true);
            a0 += lo[0]; a1 += lo[1]; a2 += hi[0]; a3 += hi[1];
        }
        e += 8;
    }
    if (e + 4 <= end) {
        unsigned int w0 = base[(size_t)csr[e+0] * 32];
        unsigned int w1 = base[(size_t)csr[e+1] * 32];
        unsigned int w2 = base[(size_t)csr[e+2] * 32];
        unsigned int w3 = base[(size_t)csr[e+3] * 32];
        #pragma unroll
        for (unsigned int w : {w0, w1, w2, w3}) {
            auto lo = __builtin_amdgcn_cvt_pk_f32_fp8(w, false);
            auto hi = __builtin_amdgcn_cvt_pk_f32_fp8(w, true);
            a0 += lo[0]; a1 += lo[1]; a2 += hi[0]; a3 += hi[1];
        }
        e += 4;
    }
    while (e < end) {
        unsigned int w = base[(size_t)csr[e++] * 32];
        auto lo = __builtin_amdgcn_cvt_pk_f32_fp8(w, false);
        auto hi = __builtin_amdgcn_cvt_pk_f32_fp8(w, true);
        a0 += lo[0]; a1 += lo[1]; a2 += hi[0]; a3 += hi[1];
    }
}

// layer-2 gather: fp8 in -> bias+relu -> fp8 out
__global__ __launch_bounds__(256) void gather_fp8_kernel(
    const unsigned int* __restrict__ hs8, const int* __restrict__ offs,
    const int* __restrict__ csr, const float* __restrict__ dinv,
    const float* __restrict__ bias, unsigned int* __restrict__ out8)
{
    int idx = blockIdx.x * 256 + threadIdx.x;
    int i  = idx >> 5;
    int f4 = idx & 31;
    const unsigned int* base = hs8 + f4;
    float a0 = 0, a1 = 0, a2 = 0, a3 = 0;
    gather_fp8_acc(base, csr, i, offs[i], offs[i + 1], a0, a1, a2, a3);
    float dv = dinv[i];
    float4 bv = *(const float4*)(bias + f4 * 4);
    float v0 = fmaxf(a0 * dv + bv.x, 0.0f);
    float v1 = fmaxf(a1 * dv + bv.y, 0.0f);
    float v2 = fmaxf(a2 * dv + bv.z, 0.0f);
    float v3 = fmaxf(a3 * dv + bv.w, 0.0f);
    int d = __builtin_amdgcn_cvt_pk_fp8_f32(v0, v1, 0, false);
    d = __builtin_amdgcn_cvt_pk_fp8_f32(v2, v3, d, true);
    out8[(size_t)i * 32 + f4] = (unsigned int)d;
}

// layer-3 gather: fp8 in -> bias (no relu) -> bf16 out
__global__ __launch_bounds__(256) void gather_fp8_bf16_kernel(
    const unsigned int* __restrict__ hs8, const int* __restrict__ offs,
    const int* __restrict__ csr, const float* __restrict__ dinv,
    const float* __restrict__ bias, unsigned int* __restrict__ outb)
{
    int idx = blockIdx.x * 256 + threadIdx.x;
    int i  = idx >> 5;
    int f4 = idx & 31;
    const unsigned int* base = hs8 + f4;
    float a0 = 0, a1 = 0, a2 = 0, a3 = 0;
    gather_fp8_acc(base, csr, i, offs[i], offs[i + 1], a0, a1, a2, a3);
    float dv = dinv[i];
    float4 bv = *(const float4*)(bias + f4 * 4);
    float v0 = a0 * dv + bv.x;
    float v1 = a1 * dv + bv.y;
    float v2 = a2 * dv + bv.z;
    float v3 = a3 * dv + bv.w;
    uint2 o;
    o.x = (unsigned int)f2bf(v0) | ((unsigned int)f2bf(v1) << 16);
    o.y = (unsigned int)f2bf(v2) | ((unsigned int)f2bf(v3) << 16);
    *(uint2*)(outb + (size_t)i * 64 + f4 * 2) = o;
}

// ---------------------------------------------------------------------------
// mean-pool: 32 rows/block; fast path when chunk is single-graph (~98%)
__global__ __launch_bounds__(128) void pool_kernel(
    const unsigned short* __restrict__ A, const int* __restrict__ batch,
    float* __restrict__ s, float* __restrict__ cnt)
{
    const int RPB = 32;
    int row0 = blockIdx.x * RPB;
    int f = threadIdx.x;
    int g0 = batch[row0];
    int g1 = batch[row0 + RPB - 1];
    if (g0 == g1) {
        float acc = 0.0f;
        #pragma unroll
        for (int r = 0; r < RPB; r++)
            acc += bf2f(A[(size_t)(row0 + r) * H_DIM + f]);
        unsafeAtomicAdd(&s[g0 * H_DIM + f], acc);
        if (f == 0) unsafeAtomicAdd(&cnt[g0], (float)RPB);
    } else {
        float acc = 0.0f;
        int cur = g0, c = 0;
        for (int r = 0; r < RPB; r++) {
            int g = batch[row0 + r];
            if (g != cur) {
                unsafeAtomicAdd(&s[cur * H_DIM + f], acc);
                if (f == 0) unsafeAtomicAdd(&cnt[cur], (float)c);
                cur = g; acc = 0.0f; c = 0;
            }
            acc += bf2f(A[(size_t)(row0 + r) * H_DIM + f]);
            c++;
        }
        unsafeAtomicAdd(&s[cur * H_DIM + f], acc);
        if (f == 0) unsafeAtomicAdd(&cnt[cur], (float)c);
    }
}

// ---------------------------------------------------------------------------
__global__ __launch_bounds__(128) void mlp_kernel(
    const float* __restrict__ s, const float* __restrict__ cnt,
    const float* __restrict__ fw1, const float* __restrict__ fb1,
    const float* __restrict__ fw2, const float* __restrict__ fb2,
    float* __restrict__ out)
{
    __shared__ float p[H_DIM];
    __shared__ float z[H_DIM];
    int g = blockIdx.x;
    int f = threadIdx.x;
    float c = fmaxf(cnt[g], 1.0f);
    p[f] = s[g * H_DIM + f] / c;
    __syncthreads();
    float acc = fb1[f];
    for (int k = 0; k < H_DIM; k++) acc = fmaf(p[k], fw1[k * H_DIM + f], acc);
    z[f] = fmaxf(acc, 0.0f);
    __syncthreads();
    if (f < C_OUT) {
        float o = fb2[f];
        for (int k = 0; k < H_DIM; k++) o = fmaf(z[k], fw2[k * C_OUT + f], o);
        out[g * C_OUT + f] = o;
    }
}

// ---------------------------------------------------------------------------
extern "C" void kernel_launch(void* const* d_in, const int* in_sizes, int n_in,
                              void* d_out, int out_size, void* d_ws, size_t ws_size,
                              hipStream_t stream)
{
    const float* x   = (const float*)d_in[0];
    const float* W1  = (const float*)d_in[1];
    const float* b1  = (const float*)d_in[2];
    const float* W2  = (const float*)d_in[3];
    const float* b2  = (const float*)d_in[4];
    const float* W3  = (const float*)d_in[5];
    const float* b3  = (const float*)d_in[6];
    const float* fw1 = (const float*)d_in[7];
    const float* fb1 = (const float*)d_in[8];
    const float* fw2 = (const float*)d_in[9];
    const float* fb2 = (const float*)d_in[10];
    const int*   ei  = (const int*)d_in[11];
    const int*   bat = (const int*)d_in[12];
    const int* esrc = ei;
    const int* edst = ei + N_EDGES;
    float* out = (float*)d_out;

    // workspace layout (aggB is a dedicated buffer — no aliasing)
    char* ws = (char*)d_ws;
    unsigned short* xb   = (unsigned short*)ws;  ws += (size_t)N_NODES * F_INPUT * 2; // 12.8MB
    unsigned short* aggA = (unsigned short*)ws;  ws += (size_t)N_NODES * F_INPUT * 2; // 12.8MB
    unsigned short* aggB = (unsigned short*)ws;  ws += (size_t)N_NODES * H_DIM * 2;   // 25.6MB
    unsigned char*  p0   = (unsigned char*)ws;   ws += (size_t)N_NODES * H_DIM;       // 12.8MB
    unsigned char*  p1   = (unsigned char*)ws;   ws += (size_t)N_NODES * H_DIM;       // 12.8MB
    unsigned char*  p2   = (unsigned char*)ws;   ws += (size_t)N_NODES * H_DIM;       // 12.8MB
    unsigned short* w1hi = (unsigned short*)ws;  ws += H_DIM * F_INPUT * 2;
    unsigned short* w1lo = (unsigned short*)ws;  ws += H_DIM * F_INPUT * 2;
    unsigned short* w2hi = (unsigned short*)ws;  ws += H_DIM * H_DIM * 2;
    unsigned short* w2lo = (unsigned short*)ws;  ws += H_DIM * H_DIM * 2;
    unsigned short* w3hi = (unsigned short*)ws;  ws += H_DIM * H_DIM * 2;
    unsigned short* w3lo = (unsigned short*)ws;  ws += H_DIM * H_DIM * 2;
    float* dinv = (float*)ws;  ws += N_NODES * 4;
    int* pre    = (int*)ws;    ws += N_NODES * 4;
    int* offs   = (int*)ws;    ws += (N_NODES + 1) * 4;
    int* bsum   = (int*)ws;    ws += (SCAN_BLOCKS + 1) * 4;
    int* slot   = (int*)ws;    ws += (size_t)N_EDGES * 4;
    int* csr    = (int*)ws;    ws += (size_t)N_EDGES * 4;
    // zero-init region (single memset): cnti | s | cnt
    int*   cnti = (int*)ws;    ws += N_NODES * 4;
    float* s    = (float*)ws;  ws += G_GRAPHS * H_DIM * 4;
    float* cnt  = (float*)ws;  ws += G_GRAPHS * 4;

    hipMemsetAsync(cnti, 0, (N_NODES + G_GRAPHS * H_DIM + G_GRAPHS) * sizeof(int), stream);

    // CSR build + dinv + x conversion
    const int egrid = (N_EDGES + 255) / 256;
    hist_kernel<<<egrid, 256, 0, stream>>>(edst, cnti, slot);
    scan1_kernel<<<SCAN_BLOCKS, 256, 0, stream>>>(cnti, pre, bsum);
    scan3x_kernel<<<SCAN_BLOCKS, 256, 0, stream>>>(
        pre, bsum, cnti, (const float4*)x, offs, dinv, (unsigned int*)xb);
    fill_kernel<<<FILL_SEG * FILL_CHUNKS, 256, 0, stream>>>(esrc, edst, offs, slot, csr);

    wpack_all_kernel<<<20, 256, 0, stream>>>(W1, W2, W3, w1hi, w1lo, w2hi, w2lo, w3hi, w3lo);

    const int gemm_grid = (N_NODES + 127) / 128;        // 782
    const int gath_grid = (N_NODES * 32) / 256;         // 12500

    // layer 1: aggregate-first (bf16 64-dim), GEMM bias+relu -> fp8
    gather_bf16_kernel<<<gath_grid, 256, 0, stream>>>(
        (const unsigned int*)xb, offs, csr, dinv, (unsigned int*)aggA);
    mfma_gemm_kernel<64, true, false, true><<<gemm_grid, 256, 0, stream>>>(
        aggA, w1hi, w1lo, dinv, b1, p0);
    // layer 2: GEMM (fp8-A, dinv) -> fp8; gather (bias+relu) -> fp8
    mfma_gemm_kernel<128, false, true, true><<<gemm_grid, 256, 0, stream>>>(
        p0, w2hi, w2lo, dinv, nullptr, p1);
    gather_fp8_kernel<<<gath_grid, 256, 0, stream>>>(
        (const unsigned int*)p1, offs, csr, dinv, b2, (unsigned int*)p2);
    // layer 3: GEMM (fp8-A, dinv) -> fp8; gather (bias) -> bf16
    mfma_gemm_kernel<128, false, true, true><<<gemm_grid, 256, 0, stream>>>(
        p2, w3hi, w3lo, dinv, nullptr, p0);
    gather_fp8_bf16_kernel<<<gath_grid, 256, 0, stream>>>(
        (const unsigned int*)p0, offs, csr, dinv, b3, (unsigned int*)aggB);

    // pool + MLP head
    pool_kernel<<<N_NODES / 32, 128, 0, stream>>>(aggB, bat, s, cnt);
    mlp_kernel<<<G_GRAPHS, 128, 0, stream>>>(s, cnt, fw1, fb1, fw2, fb2, out);
}